// Round 1
// baseline (1006.484 us; speedup 1.0000x reference)
//
#include <hip/hip_runtime.h>

// Problem: out[b,c] = dot(x[b,c,:], weight[c,:]) + bias[c]
// B=512, C=512, HW=784 (28*28). x fp32 (B,C,HW) row-contiguous.
// Memory-bound: 822 MB of x per call -> roofline ~130 us at 6.3 TB/s.

#define NB 512
#define NC 512
#define NHW 784
#define NF4 196   // NHW / 4 = 196 = 3*64 + 4

__global__ __launch_bounds__(256) void rowdot_kernel(
    const float* __restrict__ x,
    const float* __restrict__ w,
    const float* __restrict__ bias,
    float* __restrict__ out)
{
    const int wave = threadIdx.x >> 6;   // 0..3, one wave per row
    const int lane = threadIdx.x & 63;
    const long long row = ((long long)blockIdx.x << 2) + wave; // b*NC + c
    const int c = (int)(row & (NC - 1)); // NC is power of 2

    const float4* __restrict__ xr = (const float4*)(x + row * (long long)NHW);
    const float4* __restrict__ wr = (const float4*)(w + (long long)c * NHW);

    float acc = 0.0f;
    // 3 full lane-striped float4 loads per lane (covers 192 of 196)
    #pragma unroll
    for (int k = 0; k < 3; ++k) {
        float4 a  = xr[lane + k * 64];
        float4 b4 = wr[lane + k * 64];
        acc += a.x * b4.x + a.y * b4.y + a.z * b4.z + a.w * b4.w;
    }
    // tail: last 4 float4 handled by lanes 0..3
    if (lane < 4) {
        float4 a  = xr[192 + lane];
        float4 b4 = wr[192 + lane];
        acc += a.x * b4.x + a.y * b4.y + a.z * b4.z + a.w * b4.w;
    }

    // wave-64 butterfly reduction
    #pragma unroll
    for (int off = 32; off > 0; off >>= 1)
        acc += __shfl_down(acc, off, 64);

    if (lane == 0)
        out[row] = acc + bias[c];
}

extern "C" void kernel_launch(void* const* d_in, const int* in_sizes, int n_in,
                              void* d_out, int out_size, void* d_ws, size_t ws_size,
                              hipStream_t stream) {
    const float* x    = (const float*)d_in[0];  // (B, C, HW) fp32
    const float* w    = (const float*)d_in[1];  // (C, HW)    fp32
    const float* bias = (const float*)d_in[2];  // (C,)       fp32
    float* out        = (float*)d_out;          // (B, C, 1)  fp32

    const int rows = NB * NC;          // 262144
    const int blocks = rows / 4;       // 4 rows (waves) per 256-thread block
    rowdot_kernel<<<blocks, 256, 0, stream>>>(x, w, bias, out);
}

// Round 2
// 971.945 us; speedup vs baseline: 1.0355x; 1.0355x over previous
//
#include <hip/hip_runtime.h>

// out[b,c] = dot(x[b,c,:], w[c,:]) + bias[c];  B=C=512, HW=784.
// Wave w handles rows r = wid + 8192*i  ->  c = wid & 511 is wave-constant,
// so the weight row lives in registers for all 32 iterations. x is the only
// HBM stream (822 MB), double-buffered + nontemporal.

typedef float v4 __attribute__((ext_vector_type(4)));

#define NHW 784
#define NC  512
#define ROWS (512 * 512)     // 262144
#define NBLK 2048            // 4 waves/block -> 8192 waves, 32 rows each
#define WSTRIDE 8192
#define ITERS 32

__device__ __forceinline__ float dot4(v4 a, v4 b) {
    return a.x * b.x + a.y * b.y + a.z * b.z + a.w * b.w;
}

__global__ __launch_bounds__(256) void rowdot_kernel(
    const float* __restrict__ x,
    const float* __restrict__ w,
    const float* __restrict__ bias,
    float* __restrict__ out)
{
    const int lane = threadIdx.x & 63;
    const int wid  = (blockIdx.x << 2) + (threadIdx.x >> 6);  // 0..8191
    const int c    = wid & (NC - 1);                          // wave-constant
    const int tidx = 192 + (lane & 3);                        // tail idx, in-row for all lanes

    // ---- weight row -> registers, held for all 32 rows ----
    const v4* __restrict__ wr = (const v4*)(w + (long long)c * NHW);
    v4 w0 = wr[lane];
    v4 w1 = wr[lane + 64];
    v4 w2 = wr[lane + 128];
    v4 w3 = wr[tidx];                 // lanes 0..3 own the 4-v4 tail
    if (lane >= 4) { w3.x = 0.f; w3.y = 0.f; w3.z = 0.f; w3.w = 0.f; }
    const float bc = bias[c];

    // ---- prologue: load row 0 ----
    long long r = wid;
    const v4* xr = (const v4*)(x + r * (long long)NHW);
    v4 a0 = __builtin_nontemporal_load(xr + lane);
    v4 a1 = __builtin_nontemporal_load(xr + lane + 64);
    v4 a2 = __builtin_nontemporal_load(xr + lane + 128);
    v4 a3 = __builtin_nontemporal_load(xr + tidx);

    #pragma unroll 2
    for (int i = 0; i < ITERS; ++i) {
        // prefetch next row (clamped on last iter; ~3% redundant, branchless)
        const long long rn = (i + 1 < ITERS) ? r + WSTRIDE : r;
        const v4* xn = (const v4*)(x + rn * (long long)NHW);
        v4 b0 = __builtin_nontemporal_load(xn + lane);
        v4 b1 = __builtin_nontemporal_load(xn + lane + 64);
        v4 b2 = __builtin_nontemporal_load(xn + lane + 128);
        v4 b3 = __builtin_nontemporal_load(xn + tidx);

        // dot for current row (w3 zero-masked lanes kill tail duplicates)
        float acc = dot4(a0, w0) + dot4(a1, w1) + dot4(a2, w2) + dot4(a3, w3);

        #pragma unroll
        for (int off = 32; off > 0; off >>= 1)
            acc += __shfl_down(acc, off, 64);

        if (lane == 0) out[r] = acc + bc;

        a0 = b0; a1 = b1; a2 = b2; a3 = b3;
        r = rn;
    }
}

extern "C" void kernel_launch(void* const* d_in, const int* in_sizes, int n_in,
                              void* d_out, int out_size, void* d_ws, size_t ws_size,
                              hipStream_t stream) {
    const float* x    = (const float*)d_in[0];  // (B, C, HW) fp32
    const float* w    = (const float*)d_in[1];  // (C, HW)    fp32
    const float* bias = (const float*)d_in[2];  // (C,)       fp32
    float* out        = (float*)d_out;          // (B, C, 1)  fp32

    rowdot_kernel<<<NBLK, 256, 0, stream>>>(x, w, bias, out);
}